// Round 4
// baseline (323.482 us; speedup 1.0000x reference)
//
#include <hip/hip_runtime.h>

#define DT 0.001f

typedef float f2 __attribute__((ext_vector_type(2)));

// DPP row_ror ring all-reduce within each aligned row of 16 lanes.
template<int CTRL>
__device__ __forceinline__ float dpp_add(float v) {
    int r = __builtin_amdgcn_update_dpp(0, __float_as_int(v), CTRL, 0xf, 0xf, false);
    return v + __int_as_float(r);
}

// Full 32-lane group sum, result in all lanes. Wave = 2 systems:
// sysA lanes 0-31 (DPP rows 0,1), sysB lanes 32-63 (rows 2,3).
// 4 row_ror levels -> each row of 16 holds its row-sum in every lane;
// cross-16 combine via readlane broadcast + per-half select.
__device__ __forceinline__ float reduce32(float t, bool hi) {
    t = dpp_add<0x121>(t);  // row_ror:1
    t = dpp_add<0x122>(t);  // row_ror:2
    t = dpp_add<0x124>(t);  // row_ror:4
    t = dpp_add<0x128>(t);  // row_ror:8 -> row sums
    int ti = __float_as_int(t);
    float a0 = __int_as_float(__builtin_amdgcn_readlane(ti, 0));
    float a1 = __int_as_float(__builtin_amdgcn_readlane(ti, 16));
    float b0 = __int_as_float(__builtin_amdgcn_readlane(ti, 32));
    float b1 = __int_as_float(__builtin_amdgcn_readlane(ti, 48));
    float rA = a0 + a1, rB = b0 + b1;
    return hi ? rB : rA;
}

// exp(-z) for |z| <= ~0.01: degree-3 Taylor, rel error < 1e-9.
__device__ __forceinline__ float expm(float z) {
    float p = __builtin_fmaf(z, -0.16666667f, 0.5f);
    p = __builtin_fmaf(z, p, -1.0f);
    p = __builtin_fmaf(z, p, 1.0f);
    return p;
}

__device__ __forceinline__ float sumsq2(const f2& v) {
    return __builtin_fmaf(v.y, v.y, v.x * v.x);
}

template<int SE>
__device__ __forceinline__ void run(f2& x, f2& v, float& alpha, float& r, bool hi,
                                    int n_chunks, int se_rt,
                                    float c, float cE, float c2E, float hd, float hdt,
                                    f2* outx, f2* outv, int snap2, int fidx)
{
    const int se = (SE > 0) ? SE : se_rt;
    const float c2 = 2.0f * c;
    for (int ck = 1; ck <= n_chunks; ++ck) {
        // head of chunk's first step: U1, S1, U2
        alpha = __builtin_fmaf(c, r, alpha - cE);
        float s1 = expm(hdt * alpha);
        v *= s1;
        r *= s1 * s1;
        alpha = __builtin_fmaf(c, r, alpha - cE);
        // fused interior: step i tail + step i+1 head
        #pragma unroll
        for (int i = 0; i < se - 1; ++i) {
            v -= hd * x;
            x += DT * v;
            v -= hd * x;
            r = reduce32(sumsq2(v), hi);
            alpha = __builtin_fmaf(c, r, alpha - cE);     // U3
            float s2 = expm(hdt * alpha);
            r *= s2 * s2;
            alpha = __builtin_fmaf(c2, r, alpha - c2E);   // U4 + U1 (v unchanged between)
            float s1n = expm(hdt * alpha);
            v *= s2 * s1n;                                // S2 then S1 fused
            r *= s1n * s1n;
            alpha = __builtin_fmaf(c, r, alpha - cE);     // U2
        }
        // final step of chunk: clean boundary for snapshot
        v -= hd * x;
        x += DT * v;
        v -= hd * x;
        r = reduce32(sumsq2(v), hi);
        alpha = __builtin_fmaf(c, r, alpha - cE);         // U3
        float s2 = expm(hdt * alpha);
        v *= s2;
        r *= s2 * s2;
        alpha = __builtin_fmaf(c, r, alpha - cE);         // U4
        __builtin_nontemporal_store(x, &outx[(size_t)ck * snap2 + fidx]);
        __builtin_nontemporal_store(v, &outv[(size_t)ck * snap2 + fidx]);
    }
}

__global__ __launch_bounds__(256) void nh_kernel(
    const float* __restrict__ x0, const float* __restrict__ v0,
    const float* __restrict__ alpha0,
    const float* __restrict__ kT_p, const float* __restrict__ mass_p,
    const float* __restrict__ Q_p,
    const int* __restrict__ n_steps_p, const int* __restrict__ store_every_p,
    float* __restrict__ out, int B)
{
    const int D = 64;
    const int gid = blockIdx.x * blockDim.x + threadIdx.x;
    const int sys = gid >> 5;            // 32 lanes per system, 2 elems/lane
    if (sys >= B) return;
    const bool hi = (threadIdx.x & 32) != 0;  // sysB half of the wave

    const int n_steps = *n_steps_p;
    const int se      = *store_every_p;
    const int n_chunks = n_steps / se;

    const float kt = *kT_p, m = *mass_p, q = *Q_p;
    const float c   = 0.25f * DT / q;
    const float E   = (float)D * kt;
    const float cE  = c * E;
    const float c2E = 2.0f * cE;
    const float hd  = 0.5f * DT / m;
    const float hdt = 0.5f * DT;

    const int snap2 = B * 32;            // float2 slots per snapshot
    const int fidx  = gid;               // sys*32 + lane-in-group == gid

    f2 x = ((const f2*)x0)[fidx];
    f2 v = ((const f2*)v0)[fidx];
    float alpha = alpha0[sys];

    f2* outx = (f2*)out;
    f2* outv = ((f2*)out) + (size_t)(n_chunks + 1) * snap2;

    // snapshot 0
    __builtin_nontemporal_store(x, &outx[fidx]);
    __builtin_nontemporal_store(v, &outv[fidx]);

    float r = reduce32(sumsq2(v), hi);

    if (se == 10)
        run<10>(x, v, alpha, r, hi, n_chunks, se, c, cE, c2E, hd, hdt, outx, outv, snap2, fidx);
    else
        run<0>(x, v, alpha, r, hi, n_chunks, se, c, cE, c2E, hd, hdt, outx, outv, snap2, fidx);
}

extern "C" void kernel_launch(void* const* d_in, const int* in_sizes, int n_in,
                              void* d_out, int out_size, void* d_ws, size_t ws_size,
                              hipStream_t stream) {
    const float* x0     = (const float*)d_in[0];
    const float* v0     = (const float*)d_in[1];
    const float* alpha0 = (const float*)d_in[2];
    const float* kT     = (const float*)d_in[3];
    const float* mass   = (const float*)d_in[4];
    const float* Q      = (const float*)d_in[5];
    const int* n_steps  = (const int*)d_in[6];
    const int* store_ev = (const int*)d_in[7];

    const int B = in_sizes[0] / 64;       // D = 64
    const int threads = B * 32;           // 32 lanes per system
    const int block = 256;
    const int grid = (threads + block - 1) / block;

    nh_kernel<<<grid, block, 0, stream>>>(x0, v0, alpha0, kT, mass, Q,
                                          n_steps, store_ev, (float*)d_out, B);
}